// Round 9
// baseline (376.701 us; speedup 1.0000x reference)
//
#include <hip/hip_runtime.h>

#define NN 50000
#define NP 50176        // padded node stride (multiple of 256)
#define TT 518
#define KC 32
#define LL 163
#define HH 128
#define EE 1600000
#define NB 196          // node blocks: 196*256 = 50176 >= NN
#define NCOPY 8

// ---- chunked-LDS scatter, CKN=2 (100 KB histograms) ----
// R8 ledger: total = conv + edge(~75) + ~130us fixed harness fill.  Edge's
// biggest waste was the CKN=4 re-scan (each slice read 4x).  CKN=2 halves
// edge re-reads (deg 77->51 MB, coef 102->64 MB); 100 KB static LDS is safe
// (conv9 ran 113 KB).  256 blocks = 1/CU, software-pipelined scan covers
// the streaming latency.
#define CKN 2           // node chunks
#define CSZ 25088       // nodes/chunk (2*25088 = 50176), LDS acc = 100,352 B
#define PSL 128         // edge slices (partials per chunk)
#define GSC (CKN*PSL)   // 256 blocks
#define ESL (EE/PSL)    // 12500 edges per slice (divisible by 4)
#define PQ 4            // p-quarters for the two-stage partial reduction

// ---- conv10: paired 53-float windows (ancestor's proven load shape) ----
// Ledger: 53-float window = only shape that streams at ~5.2 TB/s (ancestor).
// >53 windows chain at the VGPR=128 cap (conv3/4/7); register shifting
// spills (conv5); LDS tiles hit gload_lds walls (conv2/8/9).  conv10 pairs
// two 8-l chunks per block: chunk A reads xs[53]; chunk B reads the SAME
// xs for window offsets 24..52 plus a separate ys[24] (t in [tb+53,tb+77)).
// No shifts, all indices compile-time.  Live ~= 53+24+32+8+misc ~= 125 <=
// 128 cap.  Traffic: x 1.59x (164 MB) + w 11x (70 MB) = 234 MB.
#define PAIRS 11        // ceil(21 chunks / 2): grid = NB*PAIRS = 2156
#define VS 16           // v accumulator stripes
#define VSTR 192        // stripe stride (>= LL, 16B-aligned)

// deg partials: block (chunk=b&1, p=b>>1) scans slice p, bins col hits into
// a 100 KB LDS histogram, flushes with plain stores.  Software-pipelined.
__global__ __launch_bounds__(256) void k_deg_part(const int* __restrict__ col,
                                                  const float* __restrict__ ea,
                                                  float* __restrict__ part) {
  __shared__ float acc[CSZ];
  int tid = threadIdx.x;
  for (int j = tid; j < CSZ; j += 256) acc[j] = 0.f;
  __syncthreads();
  int chunk = blockIdx.x & (CKN - 1);
  int base = chunk * CSZ;
  const int4*   c4p = (const int4*)col + (blockIdx.x >> 1) * (ESL / 4);
  const float4* a4p = (const float4*)ea + (blockIdx.x >> 1) * (ESL / 4);
  int i = tid;
  bool valid = i < ESL / 4;
  int4 c4; float4 a4;
  if (valid) { c4 = c4p[i]; a4 = a4p[i]; }
  while (valid) {
    int inext = i + 256;
    bool vnext = inext < ESL / 4;
    int4 c4n; float4 a4n;
    if (vnext) { c4n = c4p[inext]; a4n = a4p[inext]; }
    unsigned jx = (unsigned)(c4.x - base);
    unsigned jy = (unsigned)(c4.y - base);
    unsigned jz = (unsigned)(c4.z - base);
    unsigned jw = (unsigned)(c4.w - base);
    if (jx < CSZ) atomicAdd(&acc[jx], a4.x);
    if (jy < CSZ) atomicAdd(&acc[jy], a4.y);
    if (jz < CSZ) atomicAdd(&acc[jz], a4.z);
    if (jw < CSZ) atomicAdd(&acc[jw], a4.w);
    i = inext; valid = vnext; c4 = c4n; a4 = a4n;
  }
  __syncthreads();
  float* out = part + (size_t)blockIdx.x * CSZ;
  for (int j = tid; j < CSZ; j += 256) out[j] = acc[j];
}

// stage-A partial reduction: block (nb, q) sums 32 slices for 256 nodes.
__global__ __launch_bounds__(256) void k_psum(const float* __restrict__ part,
                                              float* __restrict__ part2) {
  int b = blockIdx.x;
  int nb = b % NB, q = b / NB;     // q in 0..3
  int i = nb * 256 + threadIdx.x;
  if (i >= NN) return;
  int chunk = i / CSZ, j = i - chunk * CSZ;
  const float* base = part + (size_t)chunk * CSZ + j;
  int p0 = q * (PSL / PQ);
  float s0 = 0.f, s1 = 0.f, s2 = 0.f, s3 = 0.f;
#pragma unroll
  for (int p = 0; p < PSL / PQ; p += 4) {
    s0 += base[(size_t)(p0 + p + 0) * (CKN * CSZ)];
    s1 += base[(size_t)(p0 + p + 1) * (CKN * CSZ)];
    s2 += base[(size_t)(p0 + p + 2) * (CKN * CSZ)];
    s3 += base[(size_t)(p0 + p + 3) * (CKN * CSZ)];
  }
  part2[(size_t)q * NP + i] = (s0 + s1) + (s2 + s3);
}

// dinv[i] = rsqrt(1 + sum_q part2[q][i]); also zeroes v16 (saves a dispatch)
__global__ __launch_bounds__(256) void k_dinv3(const float* __restrict__ part2,
                                               float* __restrict__ dinv,
                                               float* __restrict__ v16) {
  int tid = threadIdx.x;
  if (blockIdx.x < (VS * VSTR) / 256) v16[blockIdx.x * 256 + tid] = 0.f;
  int i = blockIdx.x * 256 + tid;
  if (i >= NN) return;
  float s = part2[i] + part2[NP + i] + part2[2 * NP + i] + part2[3 * NP + i];
  dinv[i] = rsqrtf(1.0f + s);
}

// coef partials: acc[row] += ea * dinv[col]; dinv[row] folded into k_csum3.
__global__ __launch_bounds__(256) void k_coef_part(const int* __restrict__ row,
                                                   const int* __restrict__ col,
                                                   const float* __restrict__ ea,
                                                   const float* __restrict__ dinv,
                                                   float* __restrict__ part) {
  __shared__ float acc[CSZ];
  int tid = threadIdx.x;
  for (int j = tid; j < CSZ; j += 256) acc[j] = 0.f;
  __syncthreads();
  int chunk = blockIdx.x & (CKN - 1);
  int base = chunk * CSZ;
  const int4*   r4p = (const int4*)row + (blockIdx.x >> 1) * (ESL / 4);
  const int4*   c4p = (const int4*)col + (blockIdx.x >> 1) * (ESL / 4);
  const float4* a4p = (const float4*)ea + (blockIdx.x >> 1) * (ESL / 4);
  int i = tid;
  bool valid = i < ESL / 4;
  int4 r4, c4; float4 a4;
  if (valid) { r4 = r4p[i]; c4 = c4p[i]; a4 = a4p[i]; }
  while (valid) {
    int inext = i + 256;
    bool vnext = inext < ESL / 4;
    int4 r4n, c4n; float4 a4n;
    if (vnext) { r4n = r4p[inext]; c4n = c4p[inext]; a4n = a4p[inext]; }
    float dx = dinv[c4.x], dy = dinv[c4.y], dz = dinv[c4.z], dw = dinv[c4.w];
    unsigned jx = (unsigned)(r4.x - base);
    unsigned jy = (unsigned)(r4.y - base);
    unsigned jz = (unsigned)(r4.z - base);
    unsigned jw = (unsigned)(r4.w - base);
    if (jx < CSZ) atomicAdd(&acc[jx], a4.x * dx);
    if (jy < CSZ) atomicAdd(&acc[jy], a4.y * dy);
    if (jz < CSZ) atomicAdd(&acc[jz], a4.z * dz);
    if (jw < CSZ) atomicAdd(&acc[jw], a4.w * dw);
    i = inext; valid = vnext; r4 = r4n; c4 = c4n; a4 = a4n;
  }
  __syncthreads();
  float* out = part + (size_t)blockIdx.x * CSZ;
  for (int j = tid; j < CSZ; j += 256) out[j] = acc[j];
}

// c[i] = dinv[i]^2 + dinv[i] * sum_q part2[q][i]
__global__ __launch_bounds__(256) void k_csum3(const float* __restrict__ part2,
                                               const float* __restrict__ dinv,
                                               float* __restrict__ c) {
  int i = blockIdx.x * 256 + threadIdx.x;
  if (i >= NN) return;
  float s = part2[i] + part2[NP + i] + part2[2 * NP + i] + part2[3 * NP + i];
  float di = dinv[i];
  c[i] = di * di + di * s;
}

// ---- fallback path (global-atomic version) if ws is too small ----
__global__ __launch_bounds__(256) void k_deg(const int* __restrict__ col,
                                             const float* __restrict__ ea,
                                             float* __restrict__ deg8) {
  int i = blockIdx.x * 256 + threadIdx.x;
  float* d = deg8 + (blockIdx.x & 7) * NP;
  if (i < EE / 4) {
    int4   c4 = ((const int4*)col)[i];
    float4 a4 = ((const float4*)ea)[i];
    atomicAdd(&d[c4.x], a4.x);
    atomicAdd(&d[c4.y], a4.y);
    atomicAdd(&d[c4.z], a4.z);
    atomicAdd(&d[c4.w], a4.w);
  }
}
__global__ __launch_bounds__(256) void k_dinv(const float* __restrict__ deg8,
                                              float* __restrict__ dinv) {
  int i = blockIdx.x * 256 + threadIdx.x;
  if (i < NN) {
    float s = 1.0f;
#pragma unroll
    for (int j = 0; j < NCOPY; ++j) s += deg8[j * NP + i];
    dinv[i] = rsqrtf(s);
  }
}
__global__ __launch_bounds__(256) void k_coef(const int* __restrict__ row,
                                              const int* __restrict__ col,
                                              const float* __restrict__ ea,
                                              const float* __restrict__ dinv,
                                              float* __restrict__ coef8) {
  int i = blockIdx.x * 256 + threadIdx.x;
  float* cf = coef8 + (blockIdx.x & 7) * NP;
  if (i < EE / 4) {
    int4   r4 = ((const int4*)row)[i];
    int4   c4 = ((const int4*)col)[i];
    float4 a4 = ((const float4*)ea)[i];
    atomicAdd(&cf[r4.x], a4.x * dinv[c4.x] * dinv[r4.x]);
    atomicAdd(&cf[r4.y], a4.y * dinv[c4.y] * dinv[r4.y]);
    atomicAdd(&cf[r4.z], a4.z * dinv[c4.z] * dinv[r4.z]);
    atomicAdd(&cf[r4.w], a4.w * dinv[c4.w] * dinv[r4.w]);
  }
}
__global__ __launch_bounds__(256) void k_csum(const float* __restrict__ coef8,
                                              const float* __restrict__ dinv,
                                              float* __restrict__ c) {
  int i = blockIdx.x * 256 + threadIdx.x;
  if (i < NN) {
    float di = dinv[i];
    float s = di * di;
#pragma unroll
    for (int j = 0; j < NCOPY; ++j) s += coef8[j * NP + i];
    c[i] = s;
  }
}

// v[l] += sum_n c[n]*relu(conv(x,w)+b)[l].
// conv10: thread = node (256B/wave streaming), block (nb, p) computes l in
// [16p, 16p+16) via TWO chunks sharing one window pair:
//   chunk A (l = 16p+u):   h = sum_k xs[3u+k]      * w[k]   (j <= 52)
//   chunk B (l = 16p+8+u): j = 24+3u+k in [24,76]: xs[j] if j<53 else ys[j-53]
// xs[53] covers t in [48p, 48p+53); ys[24] covers [48p+53, 48p+77).
// All loads issue before sched_barrier (ancestor-proven batching); w loaded
// LAST to keep the load-address temporaries from overlapping its live range.
// Clamped t pollutes only discarded l >= 163 (p=10 tail; proof: valid l<=162
// needs t <= 3*162+31 = 517 = TT-1).
__global__ __launch_bounds__(256, 4) void k_conv10(const float* __restrict__ x,
                                                   const float* __restrict__ cw,
                                                   const float* __restrict__ cb,
                                                   const float* __restrict__ c,
                                                   float* __restrict__ v16) {
  __shared__ float vloc[16];
  int tid = threadIdx.x;
  if (tid < 16) vloc[tid] = 0.f;
  __syncthreads();

  int nb = blockIdx.x % NB;
  int p  = blockIdx.x / NB;        // 0..10
  int n = nb * 256 + tid;
  int nc = n < NN ? n : NN - 1;    // clamp for safe loads; cn=0 kills contrib
  float cn = n < NN ? c[n] : 0.f;
  float bn = cb[nc];

  const float* xp = x + nc;
  int tb = 48 * p;
  float xs[53];
#pragma unroll
  for (int j = 0; j < 53; ++j) {
    int t = tb + j;
    t = t < TT ? t : TT - 1;
    xs[j] = xp[(size_t)t * NN];
  }
  float ys[24];
#pragma unroll
  for (int j = 0; j < 24; ++j) {
    int t = tb + 53 + j;
    t = t < TT ? t : TT - 1;
    ys[j] = xp[(size_t)t * NN];
  }
  float w[KC];
  const float4* w4 = (const float4*)(cw + (size_t)nc * KC);
#pragma unroll
  for (int k = 0; k < KC / 4; ++k) {
    float4 t4 = w4[k];
    w[4 * k] = t4.x; w[4 * k + 1] = t4.y; w[4 * k + 2] = t4.z; w[4 * k + 3] = t4.w;
  }
  __builtin_amdgcn_sched_barrier(0);   // loads stay ABOVE, compute BELOW

  int lane = tid & 63;
  // ---- chunk A: l = 16p + u ----
  {
    float accv[8];
#pragma unroll
    for (int u = 0; u < 8; ++u) {
      float h = 0.f;
#pragma unroll
      for (int k = 0; k < KC; ++k) h += xs[3 * u + k] * w[k];
      h += bn;
      h = h > 0.f ? h : 0.f;
      accv[u] = cn * h;
    }
#pragma unroll
    for (int u = 0; u < 8; ++u) {
      float val = accv[u];
      val += __shfl_xor(val, 1, 64);
      val += __shfl_xor(val, 2, 64);
      val += __shfl_xor(val, 4, 64);
      val += __shfl_xor(val, 8, 64);
      val += __shfl_xor(val, 16, 64);
      val += __shfl_xor(val, 32, 64);
      if (lane == 0) atomicAdd(&vloc[u], val);
    }
  }
  // ---- chunk B: l = 16p + 8 + u, window offset j = 24+3u+k ----
  {
    float accv[8];
#pragma unroll
    for (int u = 0; u < 8; ++u) {
      float h = 0.f;
#pragma unroll
      for (int k = 0; k < KC; ++k) {
        const int j = 24 + 3 * u + k;          // compile-time
        float xv = (j < 53) ? xs[j < 53 ? j : 0] : ys[j >= 53 ? j - 53 : 0];
        h += xv * w[k];
      }
      h += bn;
      h = h > 0.f ? h : 0.f;
      accv[u] = cn * h;
    }
#pragma unroll
    for (int u = 0; u < 8; ++u) {
      float val = accv[u];
      val += __shfl_xor(val, 1, 64);
      val += __shfl_xor(val, 2, 64);
      val += __shfl_xor(val, 4, 64);
      val += __shfl_xor(val, 8, 64);
      val += __shfl_xor(val, 16, 64);
      val += __shfl_xor(val, 32, 64);
      if (lane == 0) atomicAdd(&vloc[8 + u], val);
    }
  }
  __syncthreads();
  float* vdst = v16 + (blockIdx.x & (VS - 1)) * VSTR;
  if (tid < 16) {
    int l = 16 * p + tid;
    if (l < LL) atomicAdd(&vdst[l], vloc[tid]);
  }
}

// out[h] = (sum_l (sum_j v16[j][l]) * W[l][h]) / N + gcn_b[h]
__global__ __launch_bounds__(128) void k_out(const float* __restrict__ v16,
                                             const float* __restrict__ W,
                                             const float* __restrict__ b,
                                             float* __restrict__ out) {
  __shared__ float vs[LL];
  int h = threadIdx.x;
  for (int l = h; l < LL; l += 128) {
    float s = 0.f;
#pragma unroll
    for (int j = 0; j < VS; ++j) s += v16[j * VSTR + l];
    vs[l] = s;
  }
  __syncthreads();
  float s = 0.f;
  for (int l = 0; l < LL; ++l) s += vs[l] * W[l * HH + h];
  out[h] = s * (1.0f / NN) + b[h];
}

extern "C" void kernel_launch(void* const* d_in, const int* in_sizes, int n_in,
                              void* d_out, int out_size, void* d_ws, size_t ws_size,
                              hipStream_t stream) {
  const float* x  = (const float*)d_in[0];
  const int*   ei = (const int*)d_in[1];
  const float* ea = (const float*)d_in[2];
  const float* cw = (const float*)d_in[3];
  const float* cb = (const float*)d_in[4];
  const float* gW = (const float*)d_in[5];
  const float* gb = (const float*)d_in[6];
  float* out = (float*)d_out;

  const int* row = ei;
  const int* col = ei + EE;
  float* ws = (float*)d_ws;

  size_t need_new = ((size_t)GSC * CSZ + VS * VSTR + (2 + PQ) * NP) * sizeof(float);
  if (ws_size >= need_new) {
    float* part  = ws;                          // GSC*CSZ floats (reused deg->coef)
    float* v16   = ws + (size_t)GSC * CSZ;      // VS*VSTR floats
    float* dinv  = v16 + VS * VSTR;             // NP floats
    float* c     = dinv + NP;                   // NP floats
    float* part2 = c + NP;                      // PQ*NP floats
    k_deg_part <<<GSC, 256, 0, stream>>>(col, ea, part);
    k_psum     <<<NB * PQ, 256, 0, stream>>>(part, part2);
    k_dinv3    <<<NB, 256, 0, stream>>>(part2, dinv, v16);
    k_coef_part<<<GSC, 256, 0, stream>>>(row, col, ea, dinv, part);
    k_psum     <<<NB * PQ, 256, 0, stream>>>(part, part2);
    k_csum3    <<<NB, 256, 0, stream>>>(part2, dinv, c);
    k_conv10   <<<NB * PAIRS, 256, 0, stream>>>(x, cw, cb, c, v16);
    k_out      <<<1, 128, 0, stream>>>(v16, gW, gb, out);
  } else {
    float* deg8  = ws;
    float* coef8 = ws + NCOPY * NP;
    float* v16   = ws + 2 * NCOPY * NP;
    float* dinv  = v16 + VS * VSTR;
    float* c     = dinv + NP;
    hipMemsetAsync(deg8, 0, (2 * NCOPY * NP + VS * VSTR) * sizeof(float), stream);
    int egrid = (EE / 4 + 255) / 256;
    k_deg   <<<egrid, 256, 0, stream>>>(col, ea, deg8);
    k_dinv  <<<NB, 256, 0, stream>>>(deg8, dinv);
    k_coef  <<<egrid, 256, 0, stream>>>(row, col, ea, dinv, coef8);
    k_csum  <<<NB, 256, 0, stream>>>(coef8, dinv, c);
    k_conv10<<<NB * PAIRS, 256, 0, stream>>>(x, cw, cb, c, v16);
    k_out   <<<1, 128, 0, stream>>>(v16, gW, gb, out);
  }
}